// Round 1
// baseline (477.435 us; speedup 1.0000x reference)
//
#include <hip/hip_runtime.h>
#include <cmath>

// Problem constants (from reference)
#define IN_DIM 128
#define HID 256
#define NHEADS 4
#define NGRAPHS 32

// ---------------------------------------------------------------------------
// CSR build: count incoming edges per dst, exclusive scan, fill src lists
// ---------------------------------------------------------------------------
__global__ __launch_bounds__(256) void count_edges_k(const int* __restrict__ dst,
                                                     int* __restrict__ cnt, int E) {
  int i = blockIdx.x * 256 + threadIdx.x;
  if (i < E) atomicAdd(&cnt[dst[i]], 1);
}

__global__ __launch_bounds__(1024) void scan_k(const int* __restrict__ cnt,
                                               int* __restrict__ row_ptr,
                                               float* __restrict__ dinv, int n) {
  __shared__ int sdata[1024];
  __shared__ int s_carry;
  if (threadIdx.x == 0) s_carry = 0;
  __syncthreads();
  int nchunks = (n + 1023) >> 10;
  for (int c = 0; c < nchunks; c++) {
    int i = (c << 10) + threadIdx.x;
    int v = (i < n) ? cnt[i] : 0;
    sdata[threadIdx.x] = v;
    __syncthreads();
    for (int off = 1; off < 1024; off <<= 1) {
      int t = (threadIdx.x >= off) ? sdata[threadIdx.x - off] : 0;
      __syncthreads();
      sdata[threadIdx.x] += t;
      __syncthreads();
    }
    int excl = sdata[threadIdx.x] - v;
    if (i < n) {
      row_ptr[i] = s_carry + excl;
      // degree includes self-loop: deg = cnt_in + 1
      dinv[i] = rsqrtf((float)(v + 1));
    }
    __syncthreads();
    if (threadIdx.x == 0) s_carry += sdata[1023];
    __syncthreads();
  }
  if (threadIdx.x == 0) row_ptr[n] = s_carry;
}

__global__ __launch_bounds__(256) void fill_csr_k(const int* __restrict__ src,
                                                  const int* __restrict__ dst,
                                                  const int* __restrict__ row_ptr,
                                                  int* __restrict__ cursor,
                                                  int* __restrict__ csr_src, int E) {
  int i = blockIdx.x * 256 + threadIdx.x;
  if (i < E) {
    int d = dst[i];
    int p = atomicAdd(&cursor[d], 1);
    csr_src[row_ptr[d] + p] = src[i];
  }
}

// ---------------------------------------------------------------------------
// Tiled fp32 GEMM: C[M,N] = A[M,K] @ B[K,N].  64x64 tile, 256 thr, 4x4/thread
// ---------------------------------------------------------------------------
#define BM 64
#define BN 64
#define BK 16
#define TM 4
#define TN 4

__global__ __launch_bounds__(256) void gemm_nn_k(const float* __restrict__ A,
                                                 const float* __restrict__ B,
                                                 float* __restrict__ C,
                                                 int M, int N, int K) {
  __shared__ float As[BK][BM + 1];
  __shared__ float Bs[BK][BN];
  int tid = threadIdx.x;
  int bm = blockIdx.y * BM;
  int bn = blockIdx.x * BN;
  int tx = tid & 15, ty = tid >> 4;
  float acc[TM][TN] = {};
  for (int k0 = 0; k0 < K; k0 += BK) {
    // A tile 64x16
    #pragma unroll
    for (int l = tid; l < BM * BK; l += 256) {
      int m = l >> 4;
      int kk = l & 15;
      int gm = bm + m;
      As[kk][m] = (gm < M) ? A[(size_t)gm * K + k0 + kk] : 0.f;
    }
    // B tile 16x64
    #pragma unroll
    for (int l = tid; l < BK * BN; l += 256) {
      int kk = l >> 6;
      int nn = l & 63;
      Bs[kk][nn] = B[(size_t)(k0 + kk) * N + bn + nn];
    }
    __syncthreads();
    #pragma unroll
    for (int kk = 0; kk < BK; kk++) {
      float a[TM], b[TN];
      #pragma unroll
      for (int i = 0; i < TM; i++) a[i] = As[kk][ty * TM + i];
      #pragma unroll
      for (int j = 0; j < TN; j++) b[j] = Bs[kk][tx * TN + j];
      #pragma unroll
      for (int i = 0; i < TM; i++)
        #pragma unroll
        for (int j = 0; j < TN; j++) acc[i][j] += a[i] * b[j];
    }
    __syncthreads();
  }
  #pragma unroll
  for (int i = 0; i < TM; i++) {
    int gm = bm + ty * TM + i;
    if (gm < M) {
      #pragma unroll
      for (int j = 0; j < TN; j++) {
        C[(size_t)gm * N + bn + tx * TN + j] = acc[i][j];
      }
    }
  }
}

// ---------------------------------------------------------------------------
// GCN aggregation: out[i] = relu( sum_{s in N(i)} t[s]*dinv[s]*dinv[i]
//                                 + t[i]*dinv[i]^2 + b )
// one block per node, thread = channel
// ---------------------------------------------------------------------------
__global__ __launch_bounds__(256) void gcn_agg_k(const float* __restrict__ t,
                                                 const int* __restrict__ row_ptr,
                                                 const int* __restrict__ csr_src,
                                                 const float* __restrict__ dinv,
                                                 const float* __restrict__ bias,
                                                 float* __restrict__ out) {
  int i = blockIdx.x;
  int c = threadIdx.x;
  __shared__ int s_src[256];
  __shared__ float s_w[256];
  float di = dinv[i];
  float acc = t[(size_t)i * HID + c] * di * di;  // self loop
  int beg = row_ptr[i], end = row_ptr[i + 1];
  for (int base = beg; base < end; base += 256) {
    int m = min(256, end - base);
    if (c < m) {
      int s = csr_src[base + c];
      s_src[c] = s;
      s_w[c] = dinv[s] * di;
    }
    __syncthreads();
    for (int e = 0; e < m; e++) acc += t[(size_t)s_src[e] * HID + c] * s_w[e];
    __syncthreads();
  }
  out[(size_t)i * HID + c] = fmaxf(acc + bias[c], 0.f);
}

// ---------------------------------------------------------------------------
// GAT attention logits: a_src[n,h] = <hg[n,h,:], att_src[h,:]>, same for dst
// one block per node: 4 waves, wave h handles head h
// ---------------------------------------------------------------------------
__global__ __launch_bounds__(256) void gat_att_k(const float* __restrict__ hg,
                                                 const float* __restrict__ att_src,
                                                 const float* __restrict__ att_dst,
                                                 float* __restrict__ a_src,
                                                 float* __restrict__ a_dst) {
  int i = blockIdx.x;
  int t = threadIdx.x;
  int h = t >> 6, lane = t & 63;
  const float* row = hg + (size_t)i * (NHEADS * HID) + h * HID;
  float ss = 0.f, sd = 0.f;
  for (int c = lane; c < HID; c += 64) {
    float v = row[c];
    ss += v * att_src[h * HID + c];
    sd += v * att_dst[h * HID + c];
  }
  #pragma unroll
  for (int off = 32; off; off >>= 1) {
    ss += __shfl_down(ss, off);
    sd += __shfl_down(sd, off);
  }
  if (lane == 0) {
    a_src[i * NHEADS + h] = ss;
    a_dst[i * NHEADS + h] = sd;
  }
}

__device__ __forceinline__ float lrelu02(float x) { return x > 0.f ? x : 0.2f * x; }

// ---------------------------------------------------------------------------
// GAT aggregation with per-dst softmax over incoming edges (incl self-loop).
// passes: 1) max  2) denom  3) weighted channel gather
// ---------------------------------------------------------------------------
__global__ __launch_bounds__(256) void gat_agg_k(const float* __restrict__ hg,
                                                 const int* __restrict__ row_ptr,
                                                 const int* __restrict__ csr_src,
                                                 const float* __restrict__ a_src,
                                                 const float* __restrict__ a_dst,
                                                 const float* __restrict__ bg,
                                                 float* __restrict__ out) {
  int i = blockIdx.x;
  int t = threadIdx.x;
  int h = t >> 6, lane = t & 63;
  __shared__ float s_m[NHEADS], s_z[NHEADS];
  __shared__ int s_srcbuf[64];
  __shared__ float s_alpha[64][NHEADS];
  int beg = row_ptr[i], end = row_ptr[i + 1];
  float adst = a_dst[i * NHEADS + h];

  // pass 1: running max over edges + self-loop
  float m = -INFINITY;
  for (int e = beg + lane; e < end; e += 64) {
    int s = csr_src[e];
    m = fmaxf(m, lrelu02(a_src[s * NHEADS + h] + adst));
  }
  float vself = lrelu02(a_src[i * NHEADS + h] + adst);
  m = fmaxf(m, vself);
  #pragma unroll
  for (int off = 32; off; off >>= 1) m = fmaxf(m, __shfl_xor(m, off));

  // pass 2: denom
  float z = 0.f;
  for (int e = beg + lane; e < end; e += 64) {
    int s = csr_src[e];
    z += expf(lrelu02(a_src[s * NHEADS + h] + adst) - m);
  }
  if (lane == 0) z += expf(vself - m);
  #pragma unroll
  for (int off = 32; off; off >>= 1) z += __shfl_xor(z, off);
  if (lane == 0) {
    s_m[h] = m;
    s_z[h] = z + 1e-16f;
  }
  __syncthreads();

  // pass 3: weighted sum; thread c = channel, all 4 heads
  int c = t;
  float acc = 0.f;
  // self-loop contribution
  #pragma unroll
  for (int hh = 0; hh < NHEADS; hh++) {
    float v = lrelu02(a_src[i * NHEADS + hh] + a_dst[i * NHEADS + hh]);
    float alpha = expf(v - s_m[hh]) / s_z[hh];
    acc += alpha * hg[(size_t)i * (NHEADS * HID) + hh * HID + c];
  }
  for (int base = beg; base < end; base += 64) {
    int mc = min(64, end - base);
    if (lane < mc) {
      int s = csr_src[base + lane];
      if (h == 0) s_srcbuf[lane] = s;
      float v = lrelu02(a_src[s * NHEADS + h] + adst);
      s_alpha[lane][h] = expf(v - s_m[h]) / s_z[h];
    }
    __syncthreads();
    for (int e = 0; e < mc; e++) {
      const float* row = hg + (size_t)s_srcbuf[e] * (NHEADS * HID) + c;
      acc += s_alpha[e][0] * row[0] + s_alpha[e][1] * row[HID] +
             s_alpha[e][2] * row[2 * HID] + s_alpha[e][3] * row[3 * HID];
    }
    __syncthreads();
  }
  out[(size_t)i * HID + c] = fmaxf(acc * 0.25f + bg[c], 0.f);
}

// ---------------------------------------------------------------------------
// global mean pool (atomic accumulate) + tiny head GEMM
// ---------------------------------------------------------------------------
__global__ __launch_bounds__(256) void pool_acc_k(const float* __restrict__ h3,
                                                  const int* __restrict__ batch,
                                                  float* __restrict__ pooled,
                                                  float* __restrict__ gcnt) {
  int i = blockIdx.x;
  int c = threadIdx.x;
  int g = batch[i];
  atomicAdd(&pooled[g * HID + c], h3[(size_t)i * HID + c]);
  if (c == 0) atomicAdd(&gcnt[g], 1.f);
}

__global__ __launch_bounds__(128) void head_k(const float* __restrict__ pooled,
                                              const float* __restrict__ gcnt,
                                              const float* __restrict__ W_heads,
                                              const float* __restrict__ b_heads,
                                              float* __restrict__ out) {
  int tid = threadIdx.x;
  if (tid >= NGRAPHS * 4) return;
  int g = tid >> 2, k = tid & 3;
  float invc = 1.f / fmaxf(gcnt[g], 1.f);
  float acc = 0.f;
  for (int c = 0; c < HID; c++) acc += pooled[g * HID + c] * W_heads[c * 4 + k];
  out[g * 4 + k] = acc * invc + b_heads[k];
}

// ---------------------------------------------------------------------------
extern "C" void kernel_launch(void* const* d_in, const int* in_sizes, int n_in,
                              void* d_out, int out_size, void* d_ws, size_t ws_size,
                              hipStream_t stream) {
  const float* x = (const float*)d_in[0];
  const int* ei = (const int*)d_in[1];
  const int* batch = (const int*)d_in[2];
  const float* W1 = (const float*)d_in[3];
  const float* b1 = (const float*)d_in[4];
  const float* W2 = (const float*)d_in[5];
  const float* b2 = (const float*)d_in[6];
  const float* Wg = (const float*)d_in[7];
  const float* att_src = (const float*)d_in[8];
  const float* att_dst = (const float*)d_in[9];
  const float* bg = (const float*)d_in[10];
  const float* W_heads = (const float*)d_in[11];
  const float* b_heads = (const float*)d_in[12];
  float* out = (float*)d_out;

  const int N = in_sizes[0] / IN_DIM;   // 10000
  const int E = in_sizes[1] / 2;        // 160000
  const int* src = ei;
  const int* dst = ei + E;

  // workspace layout (256B aligned)
  char* ws = (char*)d_ws;
  size_t off = 0;
  auto take = [&](size_t bytes) -> char* {
    char* p = ws + off;
    off = (off + bytes + 255) & ~(size_t)255;
    return p;
  };
  int* cnt      = (int*)take((size_t)N * 4);
  int* row_ptr  = (int*)take((size_t)(N + 1) * 4);
  int* cursor   = (int*)take((size_t)N * 4);
  int* csr_src  = (int*)take((size_t)E * 4);
  float* dinv   = (float*)take((size_t)N * 4);
  float* a_srcv = (float*)take((size_t)N * NHEADS * 4);
  float* a_dstv = (float*)take((size_t)N * NHEADS * 4);
  float* pooled = (float*)take((size_t)NGRAPHS * HID * 4 + NGRAPHS * 4); // pooled + gcnt
  float* gcnt   = pooled + NGRAPHS * HID;
  float* t      = (float*)take((size_t)N * HID * 4);
  float* h1     = (float*)take((size_t)N * HID * 4);
  float* h2     = (float*)take((size_t)N * HID * 4);
  float* hg     = (float*)take((size_t)N * NHEADS * HID * 4);
  float* h3     = h1;  // alias: h1 dead after t2 = h1@W2

  hipMemsetAsync(cnt, 0, (size_t)N * 4, stream);
  hipMemsetAsync(cursor, 0, (size_t)N * 4, stream);
  hipMemsetAsync(pooled, 0, (size_t)NGRAPHS * HID * 4 + NGRAPHS * 4, stream);

  int eb = (E + 255) / 256;
  count_edges_k<<<eb, 256, 0, stream>>>(dst, cnt, E);
  scan_k<<<1, 1024, 0, stream>>>(cnt, row_ptr, dinv, N);
  fill_csr_k<<<eb, 256, 0, stream>>>(src, dst, row_ptr, cursor, csr_src, E);

  int mg = (N + BM - 1) / BM;
  // layer 1: t = x @ W1 ; h1 = relu(agg(t) + b1)
  gemm_nn_k<<<dim3(HID / BN, mg), 256, 0, stream>>>(x, W1, t, N, HID, IN_DIM);
  gcn_agg_k<<<N, 256, 0, stream>>>(t, row_ptr, csr_src, dinv, b1, h1);
  // layer 2: t = h1 @ W2 ; h2 = relu(agg(t) + b2)
  gemm_nn_k<<<dim3(HID / BN, mg), 256, 0, stream>>>(h1, W2, t, N, HID, HID);
  gcn_agg_k<<<N, 256, 0, stream>>>(t, row_ptr, csr_src, dinv, b2, h2);
  // GAT: hg = h2 @ Wg
  gemm_nn_k<<<dim3(NHEADS * HID / BN, mg), 256, 0, stream>>>(h2, Wg, hg, N, NHEADS * HID, HID);
  gat_att_k<<<N, 256, 0, stream>>>(hg, att_src, att_dst, a_srcv, a_dstv);
  gat_agg_k<<<N, 256, 0, stream>>>(hg, row_ptr, csr_src, a_srcv, a_dstv, bg, h3);
  // pool + heads
  pool_acc_k<<<N, 256, 0, stream>>>(h3, batch, pooled, gcnt);
  head_k<<<1, 128, 0, stream>>>(pooled, gcnt, W_heads, b_heads, out);
}

// Round 2
// 338.718 us; speedup vs baseline: 1.4095x; 1.4095x over previous
//
#include <hip/hip_runtime.h>
#include <cmath>

// Problem constants (from reference)
#define IN_DIM 128
#define HID 256
#define NHEADS 4
#define NGRAPHS 32

// ---------------------------------------------------------------------------
// CSR build: count incoming edges per dst, exclusive scan, fill src lists
// ---------------------------------------------------------------------------
__global__ __launch_bounds__(256) void count_edges_k(const int* __restrict__ dst,
                                                     int* __restrict__ cnt, int E) {
  int i = blockIdx.x * 256 + threadIdx.x;
  if (i < E) atomicAdd(&cnt[dst[i]], 1);
}

__global__ __launch_bounds__(1024) void scan_k(const int* __restrict__ cnt,
                                               int* __restrict__ row_ptr,
                                               float* __restrict__ dinv, int n) {
  __shared__ int sdata[1024];
  __shared__ int s_carry;
  if (threadIdx.x == 0) s_carry = 0;
  __syncthreads();
  int nchunks = (n + 1023) >> 10;
  for (int c = 0; c < nchunks; c++) {
    int i = (c << 10) + threadIdx.x;
    int v = (i < n) ? cnt[i] : 0;
    sdata[threadIdx.x] = v;
    __syncthreads();
    for (int off = 1; off < 1024; off <<= 1) {
      int t = (threadIdx.x >= off) ? sdata[threadIdx.x - off] : 0;
      __syncthreads();
      sdata[threadIdx.x] += t;
      __syncthreads();
    }
    int excl = sdata[threadIdx.x] - v;
    if (i < n) {
      row_ptr[i] = s_carry + excl;
      // degree includes self-loop: deg = cnt_in + 1
      dinv[i] = rsqrtf((float)(v + 1));
    }
    __syncthreads();
    if (threadIdx.x == 0) s_carry += sdata[1023];
    __syncthreads();
  }
  if (threadIdx.x == 0) row_ptr[n] = s_carry;
}

__global__ __launch_bounds__(256) void fill_csr_k(const int* __restrict__ src,
                                                  const int* __restrict__ dst,
                                                  const int* __restrict__ row_ptr,
                                                  int* __restrict__ cursor,
                                                  int* __restrict__ csr_src, int E) {
  int i = blockIdx.x * 256 + threadIdx.x;
  if (i < E) {
    int d = dst[i];
    int p = atomicAdd(&cursor[d], 1);
    csr_src[row_ptr[d] + p] = src[i];
  }
}

// ---------------------------------------------------------------------------
// Tiled fp32 GEMM: C[M,N] = A[M,K] @ B[K,N].
// Templated on TM_: tile = (16*TM_) x 64, 256 threads, per-thread TM_ x 4.
// float4 global loads for A and B; float4 C stores.
// ---------------------------------------------------------------------------
#define BK 16
#define BN 64
#define TN 4

template <int TM_>
__global__ __launch_bounds__(256) void gemm_nn_k(const float* __restrict__ A,
                                                 const float* __restrict__ B,
                                                 float* __restrict__ C,
                                                 int M, int N, int K) {
  constexpr int BM = 16 * TM_;
  __shared__ float As[BK][BM + 4];   // k-major (transposed) A tile
  __shared__ float Bs[BK][BN];
  int tid = threadIdx.x;
  int bm = blockIdx.y * BM;
  int bn = blockIdx.x * BN;
  int tx = tid & 15, ty = tid >> 4;
  float acc[TM_][TN] = {};
  for (int k0 = 0; k0 < K; k0 += BK) {
    // A tile: BM x 16, float4 loads, transpose into LDS
    #pragma unroll
    for (int it = 0; it < TM_ / 4; it++) {
      int f = tid + it * 256;
      int m = f >> 2;       // tile row
      int k4 = f & 3;       // which float4 along K
      int gm = bm + m;
      float4 v = make_float4(0.f, 0.f, 0.f, 0.f);
      if (gm < M) v = *(const float4*)&A[(size_t)gm * K + k0 + k4 * 4];
      As[k4 * 4 + 0][m] = v.x;
      As[k4 * 4 + 1][m] = v.y;
      As[k4 * 4 + 2][m] = v.z;
      As[k4 * 4 + 3][m] = v.w;
    }
    // B tile: 16 x 64, one float4 per thread
    {
      int kk = tid >> 4, n4 = tid & 15;
      *(float4*)&Bs[kk][n4 * 4] =
          *(const float4*)&B[(size_t)(k0 + kk) * N + bn + n4 * 4];
    }
    __syncthreads();
    #pragma unroll
    for (int kk = 0; kk < BK; kk++) {
      float a[TM_], b[TN];
      #pragma unroll
      for (int i = 0; i < TM_; i++) a[i] = As[kk][ty * TM_ + i];
      #pragma unroll
      for (int j = 0; j < TN; j++) b[j] = Bs[kk][tx * TN + j];
      #pragma unroll
      for (int i = 0; i < TM_; i++)
        #pragma unroll
        for (int j = 0; j < TN; j++) acc[i][j] += a[i] * b[j];
    }
    __syncthreads();
  }
  #pragma unroll
  for (int i = 0; i < TM_; i++) {
    int gm = bm + ty * TM_ + i;
    if (gm < M) {
      float4 v = make_float4(acc[i][0], acc[i][1], acc[i][2], acc[i][3]);
      *(float4*)&C[(size_t)gm * N + bn + tx * TN] = v;
    }
  }
}

// ---------------------------------------------------------------------------
// GCN aggregation: out[i] = relu( sum_{s in N(i)} t[s]*dinv[s]*dinv[i]
//                                 + t[i]*dinv[i]^2 + b )
// one block per node, thread = channel
// ---------------------------------------------------------------------------
__global__ __launch_bounds__(256) void gcn_agg_k(const float* __restrict__ t,
                                                 const int* __restrict__ row_ptr,
                                                 const int* __restrict__ csr_src,
                                                 const float* __restrict__ dinv,
                                                 const float* __restrict__ bias,
                                                 float* __restrict__ out) {
  int i = blockIdx.x;
  int c = threadIdx.x;
  __shared__ int s_src[256];
  __shared__ float s_w[256];
  float di = dinv[i];
  float acc = t[(size_t)i * HID + c] * di * di;  // self loop
  int beg = row_ptr[i], end = row_ptr[i + 1];
  for (int base = beg; base < end; base += 256) {
    int m = min(256, end - base);
    if (c < m) {
      int s = csr_src[base + c];
      s_src[c] = s;
      s_w[c] = dinv[s] * di;
    }
    __syncthreads();
    for (int e = 0; e < m; e++) acc += t[(size_t)s_src[e] * HID + c] * s_w[e];
    __syncthreads();
  }
  out[(size_t)i * HID + c] = fmaxf(acc + bias[c], 0.f);
}

// ---------------------------------------------------------------------------
// GAT attention logits: a_src[n,h] = <hg[n,h,:], att_src[h,:]>, same for dst
// one block per node: 4 waves, wave h handles head h
// ---------------------------------------------------------------------------
__global__ __launch_bounds__(256) void gat_att_k(const float* __restrict__ hg,
                                                 const float* __restrict__ att_src,
                                                 const float* __restrict__ att_dst,
                                                 float* __restrict__ a_src,
                                                 float* __restrict__ a_dst) {
  int i = blockIdx.x;
  int t = threadIdx.x;
  int h = t >> 6, lane = t & 63;
  const float* row = hg + (size_t)i * (NHEADS * HID) + h * HID;
  float ss = 0.f, sd = 0.f;
  for (int c = lane; c < HID; c += 64) {
    float v = row[c];
    ss += v * att_src[h * HID + c];
    sd += v * att_dst[h * HID + c];
  }
  #pragma unroll
  for (int off = 32; off; off >>= 1) {
    ss += __shfl_down(ss, off);
    sd += __shfl_down(sd, off);
  }
  if (lane == 0) {
    a_src[i * NHEADS + h] = ss;
    a_dst[i * NHEADS + h] = sd;
  }
}

__device__ __forceinline__ float lrelu02(float x) { return x > 0.f ? x : 0.2f * x; }

// ---------------------------------------------------------------------------
// GAT aggregation with per-dst softmax over incoming edges (incl self-loop).
// passes: 1) max  2) denom  3) weighted channel gather
// ---------------------------------------------------------------------------
__global__ __launch_bounds__(256) void gat_agg_k(const float* __restrict__ hg,
                                                 const int* __restrict__ row_ptr,
                                                 const int* __restrict__ csr_src,
                                                 const float* __restrict__ a_src,
                                                 const float* __restrict__ a_dst,
                                                 const float* __restrict__ bg,
                                                 float* __restrict__ out) {
  int i = blockIdx.x;
  int t = threadIdx.x;
  int h = t >> 6, lane = t & 63;
  __shared__ float s_m[NHEADS], s_z[NHEADS];
  __shared__ int s_srcbuf[64];
  __shared__ float s_alpha[64][NHEADS];
  int beg = row_ptr[i], end = row_ptr[i + 1];
  float adst = a_dst[i * NHEADS + h];

  // pass 1: running max over edges + self-loop
  float m = -INFINITY;
  for (int e = beg + lane; e < end; e += 64) {
    int s = csr_src[e];
    m = fmaxf(m, lrelu02(a_src[s * NHEADS + h] + adst));
  }
  float vself = lrelu02(a_src[i * NHEADS + h] + adst);
  m = fmaxf(m, vself);
  #pragma unroll
  for (int off = 32; off; off >>= 1) m = fmaxf(m, __shfl_xor(m, off));

  // pass 2: denom
  float z = 0.f;
  for (int e = beg + lane; e < end; e += 64) {
    int s = csr_src[e];
    z += expf(lrelu02(a_src[s * NHEADS + h] + adst) - m);
  }
  if (lane == 0) z += expf(vself - m);
  #pragma unroll
  for (int off = 32; off; off >>= 1) z += __shfl_xor(z, off);
  if (lane == 0) {
    s_m[h] = m;
    s_z[h] = z + 1e-16f;
  }
  __syncthreads();

  // pass 3: weighted sum; thread c = channel, all 4 heads
  int c = t;
  float acc = 0.f;
  // self-loop contribution
  #pragma unroll
  for (int hh = 0; hh < NHEADS; hh++) {
    float v = lrelu02(a_src[i * NHEADS + hh] + a_dst[i * NHEADS + hh]);
    float alpha = expf(v - s_m[hh]) / s_z[hh];
    acc += alpha * hg[(size_t)i * (NHEADS * HID) + hh * HID + c];
  }
  for (int base = beg; base < end; base += 64) {
    int mc = min(64, end - base);
    if (lane < mc) {
      int s = csr_src[base + lane];
      if (h == 0) s_srcbuf[lane] = s;
      float v = lrelu02(a_src[s * NHEADS + h] + adst);
      s_alpha[lane][h] = expf(v - s_m[h]) / s_z[h];
    }
    __syncthreads();
    for (int e = 0; e < mc; e++) {
      const float* row = hg + (size_t)s_srcbuf[e] * (NHEADS * HID) + c;
      acc += s_alpha[e][0] * row[0] + s_alpha[e][1] * row[HID] +
             s_alpha[e][2] * row[2 * HID] + s_alpha[e][3] * row[3 * HID];
    }
    __syncthreads();
  }
  out[(size_t)i * HID + c] = fmaxf(acc * 0.25f + bg[c], 0.f);
}

// ---------------------------------------------------------------------------
// Segmented global mean pool: batch is SORTED, so each block owns a
// contiguous chunk of nodes, accumulates per-channel partials in registers,
// and flushes one atomic per (segment x channel).  ~60K atomics vs 2.56M.
// ---------------------------------------------------------------------------
#define POOL_CHUNK 50
__global__ __launch_bounds__(256) void pool_acc_k(const float* __restrict__ h3,
                                                  const int* __restrict__ batch,
                                                  float* __restrict__ pooled,
                                                  float* __restrict__ gcnt, int N) {
  int c = threadIdx.x;
  int i0 = blockIdx.x * POOL_CHUNK;
  int i1 = min(i0 + POOL_CHUNK, N);
  if (i0 >= N) return;
  float acc = 0.f;
  int cur = batch[i0];
  int cnt_local = 0;
  for (int i = i0; i < i1; i++) {
    int g = batch[i];
    if (g != cur) {
      atomicAdd(&pooled[cur * HID + c], acc);
      if (c == 0) atomicAdd(&gcnt[cur], (float)cnt_local);
      acc = 0.f;
      cnt_local = 0;
      cur = g;
    }
    acc += h3[(size_t)i * HID + c];
    cnt_local++;
  }
  atomicAdd(&pooled[cur * HID + c], acc);
  if (c == 0) atomicAdd(&gcnt[cur], (float)cnt_local);
}

__global__ __launch_bounds__(128) void head_k(const float* __restrict__ pooled,
                                              const float* __restrict__ gcnt,
                                              const float* __restrict__ W_heads,
                                              const float* __restrict__ b_heads,
                                              float* __restrict__ out) {
  int tid = threadIdx.x;
  if (tid >= NGRAPHS * 4) return;
  int g = tid >> 2, k = tid & 3;
  float invc = 1.f / fmaxf(gcnt[g], 1.f);
  float acc = 0.f;
  for (int c = 0; c < HID; c++) acc += pooled[g * HID + c] * W_heads[c * 4 + k];
  out[g * 4 + k] = acc * invc + b_heads[k];
}

// ---------------------------------------------------------------------------
extern "C" void kernel_launch(void* const* d_in, const int* in_sizes, int n_in,
                              void* d_out, int out_size, void* d_ws, size_t ws_size,
                              hipStream_t stream) {
  const float* x = (const float*)d_in[0];
  const int* ei = (const int*)d_in[1];
  const int* batch = (const int*)d_in[2];
  const float* W1 = (const float*)d_in[3];
  const float* b1 = (const float*)d_in[4];
  const float* W2 = (const float*)d_in[5];
  const float* b2 = (const float*)d_in[6];
  const float* Wg = (const float*)d_in[7];
  const float* att_src = (const float*)d_in[8];
  const float* att_dst = (const float*)d_in[9];
  const float* bg = (const float*)d_in[10];
  const float* W_heads = (const float*)d_in[11];
  const float* b_heads = (const float*)d_in[12];
  float* out = (float*)d_out;

  const int N = in_sizes[0] / IN_DIM;   // 10000
  const int E = in_sizes[1] / 2;        // 160000
  const int* src = ei;
  const int* dst = ei + E;

  // workspace layout (256B aligned)
  char* ws = (char*)d_ws;
  size_t off = 0;
  auto take = [&](size_t bytes) -> char* {
    char* p = ws + off;
    off = (off + bytes + 255) & ~(size_t)255;
    return p;
  };
  int* cnt      = (int*)take((size_t)N * 4);
  int* row_ptr  = (int*)take((size_t)(N + 1) * 4);
  int* cursor   = (int*)take((size_t)N * 4);
  int* csr_src  = (int*)take((size_t)E * 4);
  float* dinv   = (float*)take((size_t)N * 4);
  float* a_srcv = (float*)take((size_t)N * NHEADS * 4);
  float* a_dstv = (float*)take((size_t)N * NHEADS * 4);
  float* pooled = (float*)take((size_t)NGRAPHS * HID * 4 + NGRAPHS * 4); // pooled + gcnt
  float* gcnt   = pooled + NGRAPHS * HID;
  float* t      = (float*)take((size_t)N * HID * 4);
  float* h1     = (float*)take((size_t)N * HID * 4);
  float* h2     = (float*)take((size_t)N * HID * 4);
  float* hg     = (float*)take((size_t)N * NHEADS * HID * 4);
  float* h3     = h1;  // alias: h1 dead after t2 = h1@W2

  hipMemsetAsync(cnt, 0, (size_t)N * 4, stream);
  hipMemsetAsync(cursor, 0, (size_t)N * 4, stream);
  hipMemsetAsync(pooled, 0, (size_t)NGRAPHS * HID * 4 + NGRAPHS * 4, stream);

  int eb = (E + 255) / 256;
  count_edges_k<<<eb, 256, 0, stream>>>(dst, cnt, E);
  scan_k<<<1, 1024, 0, stream>>>(cnt, row_ptr, dinv, N);
  fill_csr_k<<<eb, 256, 0, stream>>>(src, dst, row_ptr, cursor, csr_src, E);

  int mg64 = (N + 63) / 64;
  int mg128 = (N + 127) / 128;
  // layer 1: t = x @ W1 ; h1 = relu(agg(t) + b1)
  gemm_nn_k<4><<<dim3(HID / BN, mg64), 256, 0, stream>>>(x, W1, t, N, HID, IN_DIM);
  gcn_agg_k<<<N, 256, 0, stream>>>(t, row_ptr, csr_src, dinv, b1, h1);
  // layer 2: t = h1 @ W2 ; h2 = relu(agg(t) + b2)
  gemm_nn_k<4><<<dim3(HID / BN, mg64), 256, 0, stream>>>(h1, W2, t, N, HID, HID);
  gcn_agg_k<<<N, 256, 0, stream>>>(t, row_ptr, csr_src, dinv, b2, h2);
  // GAT: hg = h2 @ Wg  (biggest GEMM: 10000x1024x256 -> 128x64 tile)
  gemm_nn_k<8><<<dim3(NHEADS * HID / BN, mg128), 256, 0, stream>>>(h2, Wg, hg, N, NHEADS * HID, HID);
  gat_att_k<<<N, 256, 0, stream>>>(hg, att_src, att_dst, a_srcv, a_dstv);
  gat_agg_k<<<N, 256, 0, stream>>>(hg, row_ptr, csr_src, a_srcv, a_dstv, bg, h3);
  // pool + heads
  int pb = (N + POOL_CHUNK - 1) / POOL_CHUNK;
  pool_acc_k<<<pb, 256, 0, stream>>>(h3, batch, pooled, gcnt, N);
  head_k<<<1, 128, 0, stream>>>(pooled, gcnt, W_heads, b_heads, out);
}